// Round 5
// baseline (193.753 us; speedup 1.0000x reference)
//
#include <hip/hip_runtime.h>

#define N 8192
#define D 256
#define BM 128
#define NBLK ((N / BM) * (N / BM))

typedef int   i32x4 __attribute__((ext_vector_type(4)));
typedef int   i32x8 __attribute__((ext_vector_type(8)));
typedef float f32x4 __attribute__((ext_vector_type(4)));

// -------- prep: fp32 -> fp8 e4m3 (packed), norms of the DEQUANTIZED values ----
__device__ __forceinline__ unsigned pack_fp8x4(float a, float b, float c, float d) {
    unsigned lo = __builtin_amdgcn_cvt_pk_fp8_f32(a, b, 0, false);
    return __builtin_amdgcn_cvt_pk_fp8_f32(c, d, lo, true);
}
__device__ __forceinline__ float dequant_sumsq(unsigned q) {
    const float v0 = __builtin_amdgcn_cvt_f32_fp8(q, 0);
    const float v1 = __builtin_amdgcn_cvt_f32_fp8(q, 1);
    const float v2 = __builtin_amdgcn_cvt_f32_fp8(q, 2);
    const float v3 = __builtin_amdgcn_cvt_f32_fp8(q, 3);
    return fmaf(v0, v0, fmaf(v1, v1, fmaf(v2, v2, v3 * v3)));
}

// one wave per row; lane handles 4 consecutive elements (float4 in, u32 fp8x4 out)
__global__ void prep_kernel(const float* __restrict__ x1, const float* __restrict__ x2,
                            unsigned* __restrict__ x1q, unsigned* __restrict__ x2q,
                            unsigned* __restrict__ pq,
                            float* __restrict__ sq1, float* __restrict__ sq2,
                            float* __restrict__ sqp, double* __restrict__ acc,
                            unsigned* __restrict__ ctr) {
    const int tid = threadIdx.x, lane = tid & 63, wv = tid >> 6;
    const int row = blockIdx.x * 4 + wv;
    if (blockIdx.x == 0 && tid == 0) { *acc = 0.0; *ctr = 0u; }
    const size_t eb = (size_t)row * D + lane * 4;
    const float4 a = *(const float4*)(x1 + eb);
    const float4 b = *(const float4*)(x2 + eb);
    const float px = 0.5f * (a.x + b.x), py = 0.5f * (a.y + b.y);
    const float pz = 0.5f * (a.z + b.z), pw = 0.5f * (a.w + b.w);
    const unsigned qa = pack_fp8x4(a.x, a.y, a.z, a.w);
    const unsigned qb = pack_fp8x4(b.x, b.y, b.z, b.w);
    const unsigned qp = pack_fp8x4(px, py, pz, pw);
    const size_t wb = (size_t)row * (D / 4) + lane;
    x1q[wb] = qa; x2q[wb] = qb; pq[wb] = qp;
    float s1 = dequant_sumsq(qa), s2 = dequant_sumsq(qb), sp = dequant_sumsq(qp);
    #pragma unroll
    for (int o = 32; o > 0; o >>= 1) {
        s1 += __shfl_down(s1, o, 64);
        s2 += __shfl_down(s2, o, 64);
        sp += __shfl_down(sp, o, 64);
    }
    if (lane == 0) { sq1[row] = s1; sq2[row] = s2; sqp[row] = sp; }
}

// -------- main ---------------------------------------------------------------
__device__ __forceinline__ f32x4 mfma8(i32x8 a, i32x8 b, f32x4 c) {
    // cbsz=0 (A fp8 e4m3), blgp=0 (B fp8), unit E8M0 scales (0x7F -> 2^0)
    return __builtin_amdgcn_mfma_scale_f32_16x16x128_f8f6f4(
        a, b, c, 0, 0, 0, 0x7F7F7F7F, 0, 0x7F7F7F7F);
}

// fragment: 32 fp8 (k-chunk quad*32) of row m; 16B blocks XOR-swizzled by row&7
__device__ __forceinline__ i32x8 read_frag(const unsigned char* Ts, int m, int quad) {
    const int r7 = m & 7;
    const i32x4 lo = *(const i32x4*)(Ts + m * 128 + ((((2 * quad)     ^ r7)) << 4));
    const i32x4 hi = *(const i32x4*)(Ts + m * 128 + ((((2 * quad + 1) ^ r7)) << 4));
    i32x8 f;
    f[0] = lo[0]; f[1] = lo[1]; f[2] = lo[2]; f[3] = lo[3];
    f[4] = hi[0]; f[5] = hi[1]; f[6] = hi[2]; f[7] = hi[3];
    return f;
}

// stage one 128x128B tile slice: wave wv covers groups wv*4..wv*4+3 (8 rows x 1KB each)
__device__ __forceinline__ void stage_tile(const unsigned char* __restrict__ g,
                                           unsigned char* s, int base, size_t kb,
                                           int wv, int srow, int sblk) {
    #pragma unroll
    for (int it = 0; it < 4; ++it) {
        const int grp = wv * 4 + it;
        const int row = grp * 8 + srow;
        __builtin_amdgcn_global_load_lds(
            (const __attribute__((address_space(1))) void*)(g + (size_t)(base + row) * D + kb + sblk * 16),
            (__attribute__((address_space(3))) void*)(s + grp * 1024), 16, 0, 0);
    }
}

__device__ __forceinline__ float tile_logsum(const f32x4 (&acc)[4][4],
                                             const float* __restrict__ sqA,
                                             const float* __restrict__ sqB,
                                             int wr, int wc, int quad, int l15) {
    float sb[4];
    #pragma unroll
    for (int tj = 0; tj < 4; ++tj) sb[tj] = sqB[wc * 64 + tj * 16 + l15];
    float s = 0.0f;
    #pragma unroll
    for (int ti = 0; ti < 4; ++ti) {
        float sa[4];
        #pragma unroll
        for (int r = 0; r < 4; ++r) sa[r] = sqA[wr * 64 + ti * 16 + quad * 4 + r];
        #pragma unroll
        for (int tjp = 0; tjp < 2; ++tjp) {
            float pr = 1.0f;
            #pragma unroll
            for (int tj = tjp * 2; tj < tjp * 2 + 2; ++tj)
                #pragma unroll
                for (int r = 0; r < 4; ++r) {
                    float d = fmaf(-2.0f, acc[ti][tj][r], sa[r] + sb[tj]);
                    pr *= fmaxf(d, 1.0f);
                }
            s += __logf(pr);          // dist <= ~1.5e3 -> pr <= ~2.6e25, fp32-safe
        }
    }
    return s;
}

__global__ __launch_bounds__(256, 2) void mqjs_main(
    const unsigned char* __restrict__ x1q, const unsigned char* __restrict__ x2q,
    const unsigned char* __restrict__ pq,
    const float* __restrict__ sq1, const float* __restrict__ sq2,
    const float* __restrict__ sqp, double* __restrict__ acc_out,
    unsigned* __restrict__ ctr, float* __restrict__ out) {

    __shared__ __align__(16) unsigned char A1s[BM * 128];  // x1 I-tile (16 KB)
    __shared__ __align__(16) unsigned char A2s[BM * 128];  // x2 I-tile
    __shared__ __align__(16) unsigned char Bs [BM * 128];  // p J-tile (pass A) / x1 J-tile (pass B)
    __shared__ float sqa1[BM], sqa2[BM], sqbp[BM], sqbx[BM];
    __shared__ float red[4];

    const int tid = threadIdx.x;
    const int lane = tid & 63;
    const int wv = tid >> 6;
    const int wr = wv >> 1, wc = wv & 1;
    const int quad = lane >> 4, l15 = lane & 15;

    const int I0 = blockIdx.y * BM;
    const int J0 = blockIdx.x * BM;
    const bool doSym = (J0 >= I0);
    const float wse = -(float)N / (float)(N - 1);

    if (tid < BM) { sqa1[tid] = sq1[I0 + tid]; sqa2[tid] = sq2[I0 + tid]; }
    else { const int t = tid - BM; sqbp[t] = sqp[J0 + t]; sqbx[t] = sq1[J0 + t]; }

    // staging lane constants: 16B block stored at slot (lane&7), holding global
    // block (lane&7)^(row&7) (XOR swizzle; read_frag applies the inverse)
    const int srow = lane >> 3;
    const int sblk = (lane & 7) ^ srow;

    // ---------------- pass A: acc0 = x1.p^T, acc1 = x2.p^T --------------------
    f32x4 acc0[4][4], acc1[4][4];
    #pragma unroll
    for (int a = 0; a < 4; ++a)
        #pragma unroll
        for (int b = 0; b < 4; ++b) {
            acc0[a][b] = (f32x4){0.f, 0.f, 0.f, 0.f};
            acc1[a][b] = (f32x4){0.f, 0.f, 0.f, 0.f};
        }

    for (int kc = 0; kc < 2; ++kc) {
        const size_t kb = (size_t)kc * 128;
        stage_tile(x1q, A1s, I0, kb, wv, srow, sblk);
        stage_tile(x2q, A2s, I0, kb, wv, srow, sblk);
        stage_tile(pq,  Bs,  J0, kb, wv, srow, sblk);
        __syncthreads();

        i32x8 bfr[4];
        #pragma unroll
        for (int tj = 0; tj < 4; ++tj)
            bfr[tj] = read_frag(Bs, wc * 64 + tj * 16 + l15, quad);
        #pragma unroll
        for (int ti = 0; ti < 4; ++ti) {
            const i32x8 a = read_frag(A1s, wr * 64 + ti * 16 + l15, quad);
            #pragma unroll
            for (int tj = 0; tj < 4; ++tj)
                acc0[ti][tj] = mfma8(a, bfr[tj], acc0[ti][tj]);
        }
        #pragma unroll
        for (int ti = 0; ti < 4; ++ti) {
            const i32x8 a = read_frag(A2s, wr * 64 + ti * 16 + l15, quad);
            #pragma unroll
            for (int tj = 0; tj < 4; ++tj)
                acc1[ti][tj] = mfma8(a, bfr[tj], acc1[ti][tj]);
        }
        __syncthreads();
    }

    float tsum = tile_logsum(acc0, sqa1, sqbp, wr, wc, quad, l15) * 0.5f
               + tile_logsum(acc1, sqa2, sqbp, wr, wc, quad, l15) * 0.5f;

    // ---------------- pass B (upper-tri): acc2 = x1.x1^T ----------------------
    if (doSym) {
        f32x4 acc2[4][4];
        #pragma unroll
        for (int a = 0; a < 4; ++a)
            #pragma unroll
            for (int b = 0; b < 4; ++b)
                acc2[a][b] = (f32x4){0.f, 0.f, 0.f, 0.f};

        // kc descending: A1s still holds the kc=1 x1 I-tile from pass A
        for (int kc = 1; kc >= 0; --kc) {
            const size_t kb = (size_t)kc * 128;
            if (kc == 0) stage_tile(x1q, A1s, I0, kb, wv, srow, sblk);
            stage_tile(x1q, Bs, J0, kb, wv, srow, sblk);
            __syncthreads();

            i32x8 bfr[4];
            #pragma unroll
            for (int tj = 0; tj < 4; ++tj)
                bfr[tj] = read_frag(Bs, wc * 64 + tj * 16 + l15, quad);
            #pragma unroll
            for (int ti = 0; ti < 4; ++ti) {
                const i32x8 a = read_frag(A1s, wr * 64 + ti * 16 + l15, quad);
                #pragma unroll
                for (int tj = 0; tj < 4; ++tj)
                    acc2[ti][tj] = mfma8(a, bfr[tj], acc2[ti][tj]);
            }
            __syncthreads();
        }
        const float wg = (I0 == J0) ? wse : 2.0f * wse;
        tsum += tile_logsum(acc2, sqa1, sqbx, wr, wc, quad, l15) * (0.5f * wg);
    }

    // ---------------- reduce + last-block finalize ----------------------------
    #pragma unroll
    for (int o = 32; o > 0; o >>= 1) tsum += __shfl_down(tsum, o, 64);
    if (lane == 0) red[wv] = tsum;
    __syncthreads();
    if (tid == 0) {
        atomicAdd(acc_out, (double)(red[0] + red[1] + red[2] + red[3]));
        __threadfence();
        const unsigned prev = atomicAdd(ctr, 1u);
        if (prev == NBLK - 1) {
            __threadfence();
            const double tot = atomicAdd(acc_out, 0.0);   // coherent read of final sum
            out[0] = (float)(tot / (double)N);
        }
    }
}

extern "C" void kernel_launch(void* const* d_in, const int* in_sizes, int n_in,
                              void* d_out, int out_size, void* d_ws, size_t ws_size,
                              hipStream_t stream) {
    const float* x1 = (const float*)d_in[0];
    const float* x2 = (const float*)d_in[1];

    char* ws = (char*)d_ws;
    const size_t MBYTES = (size_t)N * D;                  // 2 MiB per fp8 matrix
    unsigned* x1q = (unsigned*)(ws);
    unsigned* x2q = (unsigned*)(ws + MBYTES);
    unsigned* pq  = (unsigned*)(ws + 2 * MBYTES);
    float* sq1 = (float*)(ws + 3 * MBYTES);
    float* sq2 = (float*)(ws + 3 * MBYTES + (size_t)N * 4);
    float* sqp = (float*)(ws + 3 * MBYTES + (size_t)N * 8);
    double* acc = (double*)(ws + 3 * MBYTES + (size_t)N * 12);
    unsigned* ctr = (unsigned*)(ws + 3 * MBYTES + (size_t)N * 12 + 16);

    prep_kernel<<<N / 4, 256, 0, stream>>>(x1, x2, x1q, x2q, pq, sq1, sq2, sqp, acc, ctr);
    mqjs_main<<<dim3(N / BM, N / BM), 256, 0, stream>>>(
        (const unsigned char*)x1q, (const unsigned char*)x2q, (const unsigned char*)pq,
        sq1, sq2, sqp, acc, ctr, (float*)d_out);
}

// Round 6
// 188.670 us; speedup vs baseline: 1.0269x; 1.0269x over previous
//
#include <hip/hip_runtime.h>

#define N 8192
#define D 256
#define BM 128
#define NBLK ((N / BM) * (N / BM))

typedef int   i32x4 __attribute__((ext_vector_type(4)));
typedef int   i32x8 __attribute__((ext_vector_type(8)));
typedef float f32x4 __attribute__((ext_vector_type(4)));

// -------- prep: fp32 -> fp8 e4m3 (packed), norms of the DEQUANTIZED values ----
__device__ __forceinline__ unsigned pack_fp8x4(float a, float b, float c, float d) {
    unsigned lo = __builtin_amdgcn_cvt_pk_fp8_f32(a, b, 0, false);
    return __builtin_amdgcn_cvt_pk_fp8_f32(c, d, lo, true);
}
__device__ __forceinline__ float dequant_sumsq(unsigned q) {
    const float v0 = __builtin_amdgcn_cvt_f32_fp8(q, 0);
    const float v1 = __builtin_amdgcn_cvt_f32_fp8(q, 1);
    const float v2 = __builtin_amdgcn_cvt_f32_fp8(q, 2);
    const float v3 = __builtin_amdgcn_cvt_f32_fp8(q, 3);
    return fmaf(v0, v0, fmaf(v1, v1, fmaf(v2, v2, v3 * v3)));
}

// one wave per row; lane handles 4 consecutive elements (float4 in, u32 fp8x4 out)
__global__ void prep_kernel(const float* __restrict__ x1, const float* __restrict__ x2,
                            unsigned* __restrict__ x1q, unsigned* __restrict__ x2q,
                            unsigned* __restrict__ pq,
                            float* __restrict__ sq1, float* __restrict__ sq2,
                            float* __restrict__ sqp) {
    const int tid = threadIdx.x, lane = tid & 63, wv = tid >> 6;
    const int row = blockIdx.x * 4 + wv;
    const size_t eb = (size_t)row * D + lane * 4;
    const float4 a = *(const float4*)(x1 + eb);
    const float4 b = *(const float4*)(x2 + eb);
    const float px = 0.5f * (a.x + b.x), py = 0.5f * (a.y + b.y);
    const float pz = 0.5f * (a.z + b.z), pw = 0.5f * (a.w + b.w);
    const unsigned qa = pack_fp8x4(a.x, a.y, a.z, a.w);
    const unsigned qb = pack_fp8x4(b.x, b.y, b.z, b.w);
    const unsigned qp = pack_fp8x4(px, py, pz, pw);
    const size_t wb = (size_t)row * (D / 4) + lane;
    x1q[wb] = qa; x2q[wb] = qb; pq[wb] = qp;
    float s1 = dequant_sumsq(qa), s2 = dequant_sumsq(qb), sp = dequant_sumsq(qp);
    #pragma unroll
    for (int o = 32; o > 0; o >>= 1) {
        s1 += __shfl_down(s1, o, 64);
        s2 += __shfl_down(s2, o, 64);
        sp += __shfl_down(sp, o, 64);
    }
    if (lane == 0) { sq1[row] = s1; sq2[row] = s2; sqp[row] = sp; }
}

// -------- main ---------------------------------------------------------------
__device__ __forceinline__ f32x4 mfma8(i32x8 a, i32x8 b, f32x4 c) {
    // cbsz=0 (A fp8 e4m3), blgp=0 (B fp8), unit E8M0 scales (0x7F -> 2^0)
    return __builtin_amdgcn_mfma_scale_f32_16x16x128_f8f6f4(
        a, b, c, 0, 0, 0, 0x7F7F7F7F, 0, 0x7F7F7F7F);
}

// fragment: 32 fp8 (k-chunk quad*32) of row m; 16B blocks XOR-swizzled by row&7
__device__ __forceinline__ i32x8 read_frag(const unsigned char* Ts, int m, int quad) {
    const int r7 = m & 7;
    const i32x4 lo = *(const i32x4*)(Ts + m * 128 + ((((2 * quad)     ^ r7)) << 4));
    const i32x4 hi = *(const i32x4*)(Ts + m * 128 + ((((2 * quad + 1) ^ r7)) << 4));
    i32x8 f;
    f[0] = lo[0]; f[1] = lo[1]; f[2] = lo[2]; f[3] = lo[3];
    f[4] = hi[0]; f[5] = hi[1]; f[6] = hi[2]; f[7] = hi[3];
    return f;
}

// stage one 128x128B tile slice: wave wv covers groups wv*4..wv*4+3 (8 rows x 1KB each)
__device__ __forceinline__ void stage_tile(const unsigned char* __restrict__ g,
                                           unsigned char* s, int base, size_t kb,
                                           int wv, int srow, int sblk) {
    #pragma unroll
    for (int it = 0; it < 4; ++it) {
        const int grp = wv * 4 + it;
        const int row = grp * 8 + srow;
        __builtin_amdgcn_global_load_lds(
            (const __attribute__((address_space(1))) void*)(g + (size_t)(base + row) * D + kb + sblk * 16),
            (__attribute__((address_space(3))) void*)(s + grp * 1024), 16, 0, 0);
    }
}

__device__ __forceinline__ float tile_logsum(const f32x4 (&acc)[4][4],
                                             const float* __restrict__ sqA,
                                             const float* __restrict__ sqB,
                                             int wr, int wc, int quad, int l15) {
    float sb[4];
    #pragma unroll
    for (int tj = 0; tj < 4; ++tj) sb[tj] = sqB[wc * 64 + tj * 16 + l15];
    float s = 0.0f;
    #pragma unroll
    for (int ti = 0; ti < 4; ++ti) {
        float sa[4];
        #pragma unroll
        for (int r = 0; r < 4; ++r) sa[r] = sqA[wr * 64 + ti * 16 + quad * 4 + r];
        #pragma unroll
        for (int tjp = 0; tjp < 2; ++tjp) {
            float pr = 1.0f;
            #pragma unroll
            for (int tj = tjp * 2; tj < tjp * 2 + 2; ++tj)
                #pragma unroll
                for (int r = 0; r < 4; ++r) {
                    float d = fmaf(-2.0f, acc[ti][tj][r], sa[r] + sb[tj]);
                    pr *= fmaxf(d, 1.0f);
                }
            s += __logf(pr);          // dist <= ~1.5e3 -> pr <= ~2.6e25, fp32-safe
        }
    }
    return s;
}

__global__ __launch_bounds__(256, 3) void mqjs_main(
    const unsigned char* __restrict__ x1q, const unsigned char* __restrict__ x2q,
    const unsigned char* __restrict__ pq,
    const float* __restrict__ sq1, const float* __restrict__ sq2,
    const float* __restrict__ sqp, float* __restrict__ partials) {

    __shared__ __align__(16) unsigned char A1s[BM * 128];  // x1 I-tile (16 KB)
    __shared__ __align__(16) unsigned char A2s[BM * 128];  // x2 I-tile
    __shared__ __align__(16) unsigned char Bs [BM * 128];  // p J-tile (pass A) / x1 J-tile (pass B)
    __shared__ float sqa1[BM], sqa2[BM], sqbp[BM], sqbx[BM];
    __shared__ float red[4];

    const int tid = threadIdx.x;
    const int lane = tid & 63;
    const int wv = tid >> 6;
    const int wr = wv >> 1, wc = wv & 1;
    const int quad = lane >> 4, l15 = lane & 15;

    const int I0 = blockIdx.y * BM;
    const int J0 = blockIdx.x * BM;
    const bool doSym = (J0 >= I0);
    const float wse = -(float)N / (float)(N - 1);

    if (tid < BM) { sqa1[tid] = sq1[I0 + tid]; sqa2[tid] = sq2[I0 + tid]; }
    else { const int t = tid - BM; sqbp[t] = sqp[J0 + t]; sqbx[t] = sq1[J0 + t]; }

    // staging lane constants: 16B block stored at slot (lane&7), holding global
    // block (lane&7)^(row&7) (XOR swizzle; read_frag applies the inverse)
    const int srow = lane >> 3;
    const int sblk = (lane & 7) ^ srow;

    // ---------------- pass A: acc0 = x1.p^T, acc1 = x2.p^T --------------------
    f32x4 acc0[4][4], acc1[4][4];
    #pragma unroll
    for (int a = 0; a < 4; ++a)
        #pragma unroll
        for (int b = 0; b < 4; ++b) {
            acc0[a][b] = (f32x4){0.f, 0.f, 0.f, 0.f};
            acc1[a][b] = (f32x4){0.f, 0.f, 0.f, 0.f};
        }

    for (int kc = 0; kc < 2; ++kc) {
        const size_t kb = (size_t)kc * 128;
        stage_tile(x1q, A1s, I0, kb, wv, srow, sblk);
        stage_tile(x2q, A2s, I0, kb, wv, srow, sblk);
        stage_tile(pq,  Bs,  J0, kb, wv, srow, sblk);
        __syncthreads();

        i32x8 bfr[4];
        #pragma unroll
        for (int tj = 0; tj < 4; ++tj)
            bfr[tj] = read_frag(Bs, wc * 64 + tj * 16 + l15, quad);
        #pragma unroll
        for (int ti = 0; ti < 4; ++ti) {
            const i32x8 a = read_frag(A1s, wr * 64 + ti * 16 + l15, quad);
            #pragma unroll
            for (int tj = 0; tj < 4; ++tj)
                acc0[ti][tj] = mfma8(a, bfr[tj], acc0[ti][tj]);
        }
        #pragma unroll
        for (int ti = 0; ti < 4; ++ti) {
            const i32x8 a = read_frag(A2s, wr * 64 + ti * 16 + l15, quad);
            #pragma unroll
            for (int tj = 0; tj < 4; ++tj)
                acc1[ti][tj] = mfma8(a, bfr[tj], acc1[ti][tj]);
        }
        __syncthreads();
    }

    float tsum = tile_logsum(acc0, sqa1, sqbp, wr, wc, quad, l15) * 0.5f
               + tile_logsum(acc1, sqa2, sqbp, wr, wc, quad, l15) * 0.5f;

    // ---------------- pass B (upper-tri): acc2 = x1.x1^T ----------------------
    if (doSym) {
        f32x4 acc2[4][4];
        #pragma unroll
        for (int a = 0; a < 4; ++a)
            #pragma unroll
            for (int b = 0; b < 4; ++b)
                acc2[a][b] = (f32x4){0.f, 0.f, 0.f, 0.f};

        // kc descending: A1s still holds the kc=1 x1 I-tile from pass A
        for (int kc = 1; kc >= 0; --kc) {
            const size_t kb = (size_t)kc * 128;
            if (kc == 0) stage_tile(x1q, A1s, I0, kb, wv, srow, sblk);
            stage_tile(x1q, Bs, J0, kb, wv, srow, sblk);
            __syncthreads();

            i32x8 bfr[4];
            #pragma unroll
            for (int tj = 0; tj < 4; ++tj)
                bfr[tj] = read_frag(Bs, wc * 64 + tj * 16 + l15, quad);
            #pragma unroll
            for (int ti = 0; ti < 4; ++ti) {
                const i32x8 a = read_frag(A1s, wr * 64 + ti * 16 + l15, quad);
                #pragma unroll
                for (int tj = 0; tj < 4; ++tj)
                    acc2[ti][tj] = mfma8(a, bfr[tj], acc2[ti][tj]);
            }
            __syncthreads();
        }
        const float wg = (I0 == J0) ? wse : 2.0f * wse;
        tsum += tile_logsum(acc2, sqa1, sqbx, wr, wc, quad, l15) * (0.5f * wg);
    }

    // ---------------- block reduce + contention-free partial store ------------
    #pragma unroll
    for (int o = 32; o > 0; o >>= 1) tsum += __shfl_down(tsum, o, 64);
    if (lane == 0) red[wv] = tsum;
    __syncthreads();
    if (tid == 0)
        partials[blockIdx.y * (N / BM) + blockIdx.x] = red[0] + red[1] + red[2] + red[3];
}

// reduce 4096 partials (double accumulation) -> final scalar
__global__ void finalize_kernel(const float* __restrict__ partials, float* __restrict__ out) {
    const int tid = threadIdx.x;          // 1024 threads
    const float4 v = ((const float4*)partials)[tid];
    double s = (double)v.x + (double)v.y + (double)v.z + (double)v.w;
    #pragma unroll
    for (int o = 32; o > 0; o >>= 1) s += __shfl_down(s, o, 64);
    __shared__ double r[16];
    if ((tid & 63) == 0) r[tid >> 6] = s;
    __syncthreads();
    if (tid == 0) {
        double t = 0.0;
        #pragma unroll
        for (int i = 0; i < 16; ++i) t += r[i];
        out[0] = (float)(t / (double)N);
    }
}

extern "C" void kernel_launch(void* const* d_in, const int* in_sizes, int n_in,
                              void* d_out, int out_size, void* d_ws, size_t ws_size,
                              hipStream_t stream) {
    const float* x1 = (const float*)d_in[0];
    const float* x2 = (const float*)d_in[1];

    char* ws = (char*)d_ws;
    const size_t MBYTES = (size_t)N * D;                  // 2 MiB per fp8 matrix
    unsigned* x1q = (unsigned*)(ws);
    unsigned* x2q = (unsigned*)(ws + MBYTES);
    unsigned* pq  = (unsigned*)(ws + 2 * MBYTES);
    float* sq1 = (float*)(ws + 3 * MBYTES);
    float* sq2 = (float*)(ws + 3 * MBYTES + (size_t)N * 4);
    float* sqp = (float*)(ws + 3 * MBYTES + (size_t)N * 8);
    float* partials = (float*)(ws + 3 * MBYTES + (size_t)N * 12);

    prep_kernel<<<N / 4, 256, 0, stream>>>(x1, x2, x1q, x2q, pq, sq1, sq2, sqp);
    mqjs_main<<<dim3(N / BM, N / BM), 256, 0, stream>>>(
        (const unsigned char*)x1q, (const unsigned char*)x2q, (const unsigned char*)pq,
        sq1, sq2, sqp, partials);
    finalize_kernel<<<1, 1024, 0, stream>>>(partials, (float*)d_out);
}

// Round 7
// 149.509 us; speedup vs baseline: 1.2959x; 1.2619x over previous
//
#include <hip/hip_runtime.h>

#define N 8192
#define D 256
#define BM 128
#define JG 4                      // J-tiles per block
#define GJ (N / BM / JG)          // 16
#define GI (N / BM)               // 64
#define NBLK (GJ * GI)            // 1024

typedef int   i32x4 __attribute__((ext_vector_type(4)));
typedef int   i32x8 __attribute__((ext_vector_type(8)));
typedef float f32x4 __attribute__((ext_vector_type(4)));

// -------- prep: fp32 -> fp8 e4m3 (packed), norms of the DEQUANTIZED values ----
__device__ __forceinline__ unsigned pack_fp8x4(float a, float b, float c, float d) {
    unsigned lo = __builtin_amdgcn_cvt_pk_fp8_f32(a, b, 0, false);
    return __builtin_amdgcn_cvt_pk_fp8_f32(c, d, lo, true);
}
__device__ __forceinline__ float dequant_sumsq(unsigned q) {
    const float v0 = __builtin_amdgcn_cvt_f32_fp8(q, 0);
    const float v1 = __builtin_amdgcn_cvt_f32_fp8(q, 1);
    const float v2 = __builtin_amdgcn_cvt_f32_fp8(q, 2);
    const float v3 = __builtin_amdgcn_cvt_f32_fp8(q, 3);
    return fmaf(v0, v0, fmaf(v1, v1, fmaf(v2, v2, v3 * v3)));
}

// 512 blocks; each wave handles 4 rows sequentially
__global__ void prep_kernel(const float* __restrict__ x1, const float* __restrict__ x2,
                            unsigned* __restrict__ x1q, unsigned* __restrict__ x2q,
                            unsigned* __restrict__ pq,
                            float* __restrict__ sq1, float* __restrict__ sq2,
                            float* __restrict__ sqp) {
    const int tid = threadIdx.x, lane = tid & 63, wv = tid >> 6;
    const int rowbase = blockIdx.x * 16 + wv * 4;
    for (int r = 0; r < 4; ++r) {
        const int row = rowbase + r;
        const size_t eb = (size_t)row * D + lane * 4;
        const float4 a = *(const float4*)(x1 + eb);
        const float4 b = *(const float4*)(x2 + eb);
        const float px = 0.5f * (a.x + b.x), py = 0.5f * (a.y + b.y);
        const float pz = 0.5f * (a.z + b.z), pw = 0.5f * (a.w + b.w);
        const unsigned qa = pack_fp8x4(a.x, a.y, a.z, a.w);
        const unsigned qb = pack_fp8x4(b.x, b.y, b.z, b.w);
        const unsigned qp = pack_fp8x4(px, py, pz, pw);
        const size_t wb = (size_t)row * (D / 4) + lane;
        x1q[wb] = qa; x2q[wb] = qb; pq[wb] = qp;
        float s1 = dequant_sumsq(qa), s2 = dequant_sumsq(qb), sp = dequant_sumsq(qp);
        #pragma unroll
        for (int o = 32; o > 0; o >>= 1) {
            s1 += __shfl_down(s1, o, 64);
            s2 += __shfl_down(s2, o, 64);
            sp += __shfl_down(sp, o, 64);
        }
        if (lane == 0) { sq1[row] = s1; sq2[row] = s2; sqp[row] = sp; }
    }
}

// -------- main ---------------------------------------------------------------
__device__ __forceinline__ f32x4 mfma8(i32x8 a, i32x8 b, f32x4 c) {
    return __builtin_amdgcn_mfma_scale_f32_16x16x128_f8f6f4(
        a, b, c, 0, 0, 0, 0x7F7F7F7F, 0, 0x7F7F7F7F);
}

// fragment: 32 fp8 (k-chunk quad*32) of row m; 16B blocks XOR-swizzled by row&7
__device__ __forceinline__ i32x8 read_frag(const unsigned char* Ts, int m, int quad) {
    const int r7 = m & 7;
    const i32x4 lo = *(const i32x4*)(Ts + m * 128 + ((((2 * quad)     ^ r7)) << 4));
    const i32x4 hi = *(const i32x4*)(Ts + m * 128 + ((((2 * quad + 1) ^ r7)) << 4));
    i32x8 f;
    f[0] = lo[0]; f[1] = lo[1]; f[2] = lo[2]; f[3] = lo[3];
    f[4] = hi[0]; f[5] = hi[1]; f[6] = hi[2]; f[7] = hi[3];
    return f;
}

// stage one 128x128B K-chunk (16 KB): wave wv covers groups wv*4..wv*4+3
__device__ __forceinline__ void stage_tile(const unsigned char* __restrict__ g,
                                           unsigned char* s, int rowbase, size_t kb,
                                           int wv, int srow, int sblk) {
    #pragma unroll
    for (int it = 0; it < 4; ++it) {
        const int grp = wv * 4 + it;
        const int row = grp * 8 + srow;
        __builtin_amdgcn_global_load_lds(
            (const __attribute__((address_space(1))) void*)(g + (size_t)(rowbase + row) * D + kb + sblk * 16),
            (__attribute__((address_space(3))) void*)(s + grp * 1024), 16, 0, 0);
    }
}

__device__ __forceinline__ float tile_logsum(const f32x4 (&acc)[4][4],
                                             const float* __restrict__ sqA_lds,
                                             const float sb[4],
                                             int wr, int quad) {
    float s = 0.0f;
    #pragma unroll
    for (int ti = 0; ti < 4; ++ti) {
        float sa[4];
        #pragma unroll
        for (int r = 0; r < 4; ++r) sa[r] = sqA_lds[wr * 64 + ti * 16 + quad * 4 + r];
        #pragma unroll
        for (int tjp = 0; tjp < 2; ++tjp) {
            float pr = 1.0f;
            #pragma unroll
            for (int tj = tjp * 2; tj < tjp * 2 + 2; ++tj)
                #pragma unroll
                for (int r = 0; r < 4; ++r) {
                    float d = fmaf(-2.0f, acc[ti][tj][r], sa[r] + sb[tj]);
                    pr *= fmaxf(d, 1.0f);
                }
            s += __logf(pr);          // dist <= ~1.5e3 -> pr <= ~2.6e25, fp32-safe
        }
    }
    return s;
}

__global__ __launch_bounds__(256, 1) void mqjs_main(
    const unsigned char* __restrict__ x1q, const unsigned char* __restrict__ x2q,
    const unsigned char* __restrict__ pq,
    const float* __restrict__ sq1, const float* __restrict__ sq2,
    const float* __restrict__ sqp, float* __restrict__ partials) {

    // 129 KB LDS -> one block per CU by design
    __shared__ __align__(16) unsigned char A1s[2 * BM * 128]; // x1 I-tile, both kc (32 KB)
    __shared__ __align__(16) unsigned char A2s[2 * BM * 128]; // x2 I-tile, both kc
    __shared__ __align__(16) unsigned char BAs[2 * BM * 128]; // p  J-tile, both kc
    __shared__ __align__(16) unsigned char BBs[2 * BM * 128]; // x1 J-tile, both kc
    __shared__ float sqa1[BM], sqa2[BM];
    __shared__ float red[4];

    const int tid = threadIdx.x;
    const int lane = tid & 63;
    const int wv = tid >> 6;
    const int wr = wv >> 1, wc = wv & 1;
    const int quad = lane >> 4, l15 = lane & 15;

    const int I0 = blockIdx.y * BM;
    const int jbase = blockIdx.x * JG;                  // J-tile index base
    const float wse = -(float)N / (float)(N - 1);

    const int srow = lane >> 3;
    const int sblk = (lane & 7) ^ srow;

    // initial staging: A (both matrices, both kc) + first p J-tile
    stage_tile(x1q, A1s,         I0, 0,   wv, srow, sblk);
    stage_tile(x1q, A1s + 16384, I0, 128, wv, srow, sblk);
    stage_tile(x2q, A2s,         I0, 0,   wv, srow, sblk);
    stage_tile(x2q, A2s + 16384, I0, 128, wv, srow, sblk);
    stage_tile(pq,  BAs,         jbase * BM, 0,   wv, srow, sblk);
    stage_tile(pq,  BAs + 16384, jbase * BM, 128, wv, srow, sblk);
    if (tid < BM) sqa1[tid] = sq1[I0 + tid];
    else          sqa2[tid - BM] = sq2[I0 + tid - BM];
    if (tid >= BM) sqa1[tid - BM] = sq1[I0 + tid - BM];
    else           sqa2[tid] = sq2[I0 + tid];
    __syncthreads();

    // cache x1 I-fragments in registers for the whole block (used in both passes)
    i32x8 a1f[2][4];
    #pragma unroll
    for (int kc = 0; kc < 2; ++kc)
        #pragma unroll
        for (int ti = 0; ti < 4; ++ti)
            a1f[kc][ti] = read_frag(A1s + kc * 16384, wr * 64 + ti * 16 + l15, quad);

    float tsum = 0.0f;

    for (int jj = 0; jj < JG; ++jj) {
        const int J0 = (jbase + jj) * BM;
        const bool doSym = (J0 >= I0);

        // ---- pass A: acc0 = x1.p^T, acc1 = x2.p^T (BAs ready via last barrier)
        f32x4 acc0[4][4], acc1[4][4];
        #pragma unroll
        for (int a = 0; a < 4; ++a)
            #pragma unroll
            for (int b = 0; b < 4; ++b) {
                acc0[a][b] = (f32x4){0.f, 0.f, 0.f, 0.f};
                acc1[a][b] = (f32x4){0.f, 0.f, 0.f, 0.f};
            }
        #pragma unroll
        for (int kc = 0; kc < 2; ++kc) {
            i32x8 bfr[4];
            #pragma unroll
            for (int tj = 0; tj < 4; ++tj)
                bfr[tj] = read_frag(BAs + kc * 16384, wc * 64 + tj * 16 + l15, quad);
            #pragma unroll
            for (int ti = 0; ti < 4; ++ti) {
                const i32x8 a2 = read_frag(A2s + kc * 16384, wr * 64 + ti * 16 + l15, quad);
                #pragma unroll
                for (int tj = 0; tj < 4; ++tj) {
                    acc0[ti][tj] = mfma8(a1f[kc][ti], bfr[tj], acc0[ti][tj]);
                    acc1[ti][tj] = mfma8(a2,          bfr[tj], acc1[ti][tj]);
                }
            }
        }

        // issue x1 J-tile stage now; epilogue below hides the flight time
        if (doSym) {
            stage_tile(x1q, BBs,         J0, 0,   wv, srow, sblk);
            stage_tile(x1q, BBs + 16384, J0, 128, wv, srow, sblk);
        }

        {   // epilogue for acc0/acc1 (sqB = |p|^2 from global, coalesced)
            float sbp[4];
            #pragma unroll
            for (int tj = 0; tj < 4; ++tj) sbp[tj] = sqp[J0 + wc * 64 + tj * 16 + l15];
            tsum += 0.5f * tile_logsum(acc0, sqa1, sbp, wr, quad);
            tsum += 0.5f * tile_logsum(acc1, sqa2, sbp, wr, quad);
        }
        __syncthreads();   // BBs ready; all waves done reading BAs

        // ---- pass B: acc2 = x1.x1^T (upper-tri only)
        f32x4 acc2[4][4];
        if (doSym) {
            #pragma unroll
            for (int a = 0; a < 4; ++a)
                #pragma unroll
                for (int b = 0; b < 4; ++b)
                    acc2[a][b] = (f32x4){0.f, 0.f, 0.f, 0.f};
            #pragma unroll
            for (int kc = 0; kc < 2; ++kc) {
                i32x8 bfr[4];
                #pragma unroll
                for (int tj = 0; tj < 4; ++tj)
                    bfr[tj] = read_frag(BBs + kc * 16384, wc * 64 + tj * 16 + l15, quad);
                #pragma unroll
                for (int ti = 0; ti < 4; ++ti)
                    #pragma unroll
                    for (int tj = 0; tj < 4; ++tj)
                        acc2[ti][tj] = mfma8(a1f[kc][ti], bfr[tj], acc2[ti][tj]);
            }
        }

        // issue next p J-tile stage into BAs (safe: barrier above); epilogue hides it
        if (jj < JG - 1) {
            stage_tile(pq, BAs,         (jbase + jj + 1) * BM, 0,   wv, srow, sblk);
            stage_tile(pq, BAs + 16384, (jbase + jj + 1) * BM, 128, wv, srow, sblk);
        }

        if (doSym) {
            float sbx[4];
            #pragma unroll
            for (int tj = 0; tj < 4; ++tj) sbx[tj] = sq1[J0 + wc * 64 + tj * 16 + l15];
            const float wg = (I0 == J0) ? wse : 2.0f * wse;
            tsum += (0.5f * wg) * tile_logsum(acc2, sqa1, sbx, wr, quad);
        }
        __syncthreads();   // next BAs ready; all waves done reading BBs
    }

    // ---- block reduce + contention-free partial store
    #pragma unroll
    for (int o = 32; o > 0; o >>= 1) tsum += __shfl_down(tsum, o, 64);
    if (lane == 0) red[wv] = tsum;
    __syncthreads();
    if (tid == 0)
        partials[blockIdx.y * GJ + blockIdx.x] = red[0] + red[1] + red[2] + red[3];
}

// reduce 1024 partials (double accumulation) -> final scalar
__global__ void finalize_kernel(const float* __restrict__ partials, float* __restrict__ out) {
    const int tid = threadIdx.x;          // 256 threads
    const float4 v = ((const float4*)partials)[tid];
    double s = (double)v.x + (double)v.y + (double)v.z + (double)v.w;
    #pragma unroll
    for (int o = 32; o > 0; o >>= 1) s += __shfl_down(s, o, 64);
    __shared__ double r[4];
    if ((tid & 63) == 0) r[tid >> 6] = s;
    __syncthreads();
    if (tid == 0) out[0] = (float)((r[0] + r[1] + r[2] + r[3]) / (double)N);
}

extern "C" void kernel_launch(void* const* d_in, const int* in_sizes, int n_in,
                              void* d_out, int out_size, void* d_ws, size_t ws_size,
                              hipStream_t stream) {
    const float* x1 = (const float*)d_in[0];
    const float* x2 = (const float*)d_in[1];

    char* ws = (char*)d_ws;
    const size_t MBYTES = (size_t)N * D;                  // 2 MiB per fp8 matrix
    unsigned* x1q = (unsigned*)(ws);
    unsigned* x2q = (unsigned*)(ws + MBYTES);
    unsigned* pq  = (unsigned*)(ws + 2 * MBYTES);
    float* sq1 = (float*)(ws + 3 * MBYTES);
    float* sq2 = (float*)(ws + 3 * MBYTES + (size_t)N * 4);
    float* sqp = (float*)(ws + 3 * MBYTES + (size_t)N * 8);
    float* partials = (float*)(ws + 3 * MBYTES + (size_t)N * 12);

    prep_kernel<<<N / 16, 256, 0, stream>>>(x1, x2, x1q, x2q, pq, sq1, sq2, sqp);
    mqjs_main<<<dim3(GJ, GI), 256, 0, stream>>>(
        (const unsigned char*)x1q, (const unsigned char*)x2q, (const unsigned char*)pq,
        sq1, sq2, sqp, partials);
    finalize_kernel<<<1, 256, 0, stream>>>(partials, (float*)d_out);
}